// Round 1
// baseline (84330.792 us; speedup 1.0000x reference)
//
#include <hip/hip_runtime.h>
#include <stdint.h>

// VanillaRNN — Round 10: async LDS-staged W with 4-deep ring + counted vmcnt.
//
// R9 post-mortem: dur == hbm_bytes/877GB/s exactly -> latency/concurrency-bound
// on W refetch (83% L2 hit, 17% miss at ~900cy, 1 wave/SIMD, ~4KB/wave in
// flight). Fix: cooperative 32KB-block DMA of W via global_load_lds (16B/lane),
// 4-buffer LDS ring (128KB), s_waitcnt vmcnt(8) + raw s_barrier per block —
// prefetch never drains (T3/T4). W consumed from LDS (ds_read_b32, 2-way free).
//
// Golden universe unchanged (decoded R4-R6): pure f32;
//   xh = chain_{k} fmaf(x[k], W_xh[k][j]); xh += b_h[j]
//   m  = chain_{i} fmaf(h[i], W_hh[i][j])   (single ascending chain)
//   h' = eigen_tanhf_fma(xh + m)
// Chain order frozen (chaos ~3.3x/step). Only load SOURCE changed vs R9.
//
// State now planar: hti[step][batch][512], xti[step][batch][128] so the x DMA
// destination is linear in lane (global_load_lds writes base+lane*16).

#define BATCH   256
#define SEQ     1024
#define IN_DIM  128
#define HIDDEN  512
#define CLASSES 128
#define NWG     (BATCH / 2)   // 128

#define BLK_ROWS   16
#define BLK_FLOATS (BLK_ROWS * HIDDEN)            // 8192 floats = 32 KB
#define NBLK       ((IN_DIM + HIDDEN) / BLK_ROWS) // 40 blocks/step
#define XH_BLKS    (IN_DIM / BLK_ROWS)            // 8

typedef const __attribute__((address_space(1))) void* gas_t;
typedef __attribute__((address_space(3))) void* las_t;

// counted-vmcnt block sync: wait for oldest block (3 in flight x 4 loads),
// raw barrier (NO vmcnt(0) drain — that's the __syncthreads trap).
#define BLOCK_SYNC() do { \
    asm volatile("s_waitcnt vmcnt(8) lgkmcnt(0)" ::: "memory"); \
    __builtin_amdgcn_s_barrier(); \
    asm volatile("" ::: "memory"); \
} while (0)

// ---- Eigen/XLA rational tanh f32, FMA variant — verbatim R5 ----
__device__ __forceinline__ float eigen_tanhf_fma(float ax) {
#pragma clang fp contract(off)
    const float pc = 7.99881172180175781f, mc = -7.99881172180175781f;
    float x = fmaxf(fminf(ax, pc), mc);
    float x2 = x * x;
    float p = __builtin_fmaf(x2, -2.76076847742355e-16f, 2.00018790482477e-13f);
    p = __builtin_fmaf(x2, p, -8.60467152213735e-11f);
    p = __builtin_fmaf(x2, p, 5.12229709037114e-08f);
    p = __builtin_fmaf(x2, p, 1.48572235717979e-05f);
    p = __builtin_fmaf(x2, p, 6.37261928875436e-04f);
    p = __builtin_fmaf(x2, p, 4.89352455891786e-03f);
    p = x * p;
    float q = __builtin_fmaf(x2, 1.19825839466702e-06f, 1.18534705686654e-04f);
    q = __builtin_fmaf(x2, q, 2.26843463243900e-03f);
    q = __builtin_fmaf(x2, q, 4.89352518554385e-03f);
    float r = p / q;
    return (fabsf(ax) < 0.0004f) ? ax : r;
}

// stage one 32KB W block: 512 threads x 4 x dwordx4 (16B), linear dest.
__device__ __forceinline__ void stage_block(const float* __restrict__ src,
                                            float* __restrict__ dst, int tid)
{
    const float* gp = src + tid * 4;
    float* lp = dst + tid * 4;
#pragma unroll
    for (int i = 0; i < 4; ++i) {
        __builtin_amdgcn_global_load_lds((gas_t)(gp + i * 2048),
                                         (las_t)(lp + i * 2048), 16, 0, 0);
    }
}

// 16 rows of the frozen fmaf chain. Per-accumulator order identical to R9:
// rows ascending; batch0 (s0) then batch1 (s1) per row.
__device__ __forceinline__ void fma16(const float* __restrict__ wc,
                                      const float* __restrict__ p0,
                                      const float* __restrict__ p1,
                                      float& s0, float& s1)
{
#pragma clang fp contract(off)
    const float w00 = wc[ 0*HIDDEN], w01 = wc[ 1*HIDDEN], w02 = wc[ 2*HIDDEN], w03 = wc[ 3*HIDDEN];
    const float w04 = wc[ 4*HIDDEN], w05 = wc[ 5*HIDDEN], w06 = wc[ 6*HIDDEN], w07 = wc[ 7*HIDDEN];
    const float w08 = wc[ 8*HIDDEN], w09 = wc[ 9*HIDDEN], w10 = wc[10*HIDDEN], w11 = wc[11*HIDDEN];
    const float w12 = wc[12*HIDDEN], w13 = wc[13*HIDDEN], w14 = wc[14*HIDDEN], w15 = wc[15*HIDDEN];
    const float4 u0 = *(const float4*)(p0 +  0);
    const float4 u1 = *(const float4*)(p0 +  4);
    const float4 u2 = *(const float4*)(p0 +  8);
    const float4 u3 = *(const float4*)(p0 + 12);
    const float4 v0 = *(const float4*)(p1 +  0);
    const float4 v1 = *(const float4*)(p1 +  4);
    const float4 v2 = *(const float4*)(p1 +  8);
    const float4 v3 = *(const float4*)(p1 + 12);
    s0 = __builtin_fmaf(u0.x, w00, s0); s1 = __builtin_fmaf(v0.x, w00, s1);
    s0 = __builtin_fmaf(u0.y, w01, s0); s1 = __builtin_fmaf(v0.y, w01, s1);
    s0 = __builtin_fmaf(u0.z, w02, s0); s1 = __builtin_fmaf(v0.z, w02, s1);
    s0 = __builtin_fmaf(u0.w, w03, s0); s1 = __builtin_fmaf(v0.w, w03, s1);
    s0 = __builtin_fmaf(u1.x, w04, s0); s1 = __builtin_fmaf(v1.x, w04, s1);
    s0 = __builtin_fmaf(u1.y, w05, s0); s1 = __builtin_fmaf(v1.y, w05, s1);
    s0 = __builtin_fmaf(u1.z, w06, s0); s1 = __builtin_fmaf(v1.z, w06, s1);
    s0 = __builtin_fmaf(u1.w, w07, s0); s1 = __builtin_fmaf(v1.w, w07, s1);
    s0 = __builtin_fmaf(u2.x, w08, s0); s1 = __builtin_fmaf(v2.x, w08, s1);
    s0 = __builtin_fmaf(u2.y, w09, s0); s1 = __builtin_fmaf(v2.y, w09, s1);
    s0 = __builtin_fmaf(u2.z, w10, s0); s1 = __builtin_fmaf(v2.z, w10, s1);
    s0 = __builtin_fmaf(u2.w, w11, s0); s1 = __builtin_fmaf(v2.w, w11, s1);
    s0 = __builtin_fmaf(u3.x, w12, s0); s1 = __builtin_fmaf(v3.x, w12, s1);
    s0 = __builtin_fmaf(u3.y, w13, s0); s1 = __builtin_fmaf(v3.y, w13, s1);
    s0 = __builtin_fmaf(u3.z, w14, s0); s1 = __builtin_fmaf(v3.z, w14, s1);
    s0 = __builtin_fmaf(u3.w, w15, s0); s1 = __builtin_fmaf(v3.w, w15, s1);
}

__global__ __launch_bounds__(HIDDEN)
void rnn_fast(const float* __restrict__ x,
              const float* __restrict__ W_hh,
              const float* __restrict__ W_xh,
              const float* __restrict__ W_hy,
              const float* __restrict__ b_h,
              const float* __restrict__ b_y,
              float* __restrict__ out)
{
    __shared__ alignas(16) float wbuf[4][BLK_FLOATS];  // 128 KB ring
    __shared__ alignas(16) float hti[2][2][HIDDEN];    // 8 KB  [step][batch][row]
    __shared__ alignas(16) float xti[2][2][IN_DIM];    // 2 KB  [step][batch][k]

    const int j = threadIdx.x;   // hidden column
    const int g = blockIdx.x;

    const float bh = b_h[j];
    const float* xb0 = x + (size_t)(2 * g) * SEQ * IN_DIM;
    const float* xb1 = xb0 + (size_t)SEQ * IN_DIM;

    hti[0][0][j] = 0.0f;
    hti[0][1][j] = 0.0f;

    // x_0 DMA (wave 0 only; dest linear in lane across [b][k] planar layout).
    // Issued FIRST so it's oldest in wave0's FIFO -> drained by BLOCK_SYNC(0).
    if (j < 64) {
        const float* gsrc = ((j < 32) ? xb0 : xb1) + (j & 31) * 4;
        __builtin_amdgcn_global_load_lds((gas_t)gsrc,
                                         (las_t)(&xti[0][0][0] + j * 4), 16, 0, 0);
    }
    // prologue: blocks 0,1,2 (all W_xh) -> ring slots 0,1,2
    stage_block(W_xh,                  wbuf[0], j);
    stage_block(W_xh + 1 * BLK_FLOATS, wbuf[1], j);
    stage_block(W_xh + 2 * BLK_FLOATS, wbuf[2], j);

    for (int t = 0; t < SEQ; ++t) {
        const int cur = t & 1, nxt = cur ^ 1;

        // ---- xh chain: blocks 0..7 (rows 0..127 of W_xh) ----
        float a0 = 0.0f, a1 = 0.0f;
#pragma unroll
        for (int b = 0; b < XH_BLKS; ++b) {
            BLOCK_SYNC();
            {   // prefetch block b+3 (3..10, no wrap here)
                const int bm = b + 3;
                const float* src = (bm < XH_BLKS)
                                 ? (W_xh + (size_t)bm * BLK_FLOATS)
                                 : (W_hh + (size_t)(bm - XH_BLKS) * BLK_FLOATS);
                stage_block(src, wbuf[(b + 3) & 3], j);
            }
            fma16(&wbuf[b & 3][j],
                  &xti[cur][0][b * BLK_ROWS], &xti[cur][1][b * BLK_ROWS], a0, a1);
        }
        a0 = a0 + bh;
        a1 = a1 + bh;

        // ---- hh chain: blocks 8..39 (rows 0..511 of W_hh) ----
        float m0 = 0.0f, m1 = 0.0f;
#pragma unroll 4
        for (int b8 = 0; b8 < 32; ++b8) {
            BLOCK_SYNC();
            {   // prefetch global block (8+b8)+3, wrapping into next step
                int bm = b8 + 11;
                if (bm >= NBLK) bm -= NBLK;
                const float* src = (bm < XH_BLKS)
                                 ? (W_xh + (size_t)bm * BLK_FLOATS)
                                 : (W_hh + (size_t)(bm - XH_BLKS) * BLK_FLOATS);
                stage_block(src, wbuf[(b8 + 3) & 3], j);
            }
            // x_{t+1} DMA mid-stream (wave 0): FIFO position guarantees it
            // drains by SYNC(b8=25) — long before next step's xh reads.
            if (b8 == 22 && j < 64 && t + 1 < SEQ) {
                const float* gsrc = ((j < 32) ? xb0 : xb1)
                                  + (size_t)(t + 1) * IN_DIM + (j & 31) * 4;
                __builtin_amdgcn_global_load_lds((gas_t)gsrc,
                                                 (las_t)(&xti[nxt][0][0] + j * 4),
                                                 16, 0, 0);
            }
            fma16(&wbuf[b8 & 3][j],
                  &hti[cur][0][b8 * BLK_ROWS], &hti[cur][1][b8 * BLK_ROWS], m0, m1);
        }

        const float h0 = eigen_tanhf_fma(a0 + m0);
        const float h1 = eigen_tanhf_fma(a1 + m1);
        hti[nxt][0][j] = h0;   // visibility ordered by next BLOCK_SYNC's
        hti[nxt][1][j] = h1;   // lgkmcnt(0)+barrier (first read is at b8=0, t+1)
    }

    // ---- head: out[2g+b, c] = h_final[b,:] @ W_hy[:,c] + b_y[c] ----
    asm volatile("s_waitcnt lgkmcnt(0)" ::: "memory");
    __builtin_amdgcn_s_barrier();
    asm volatile("" ::: "memory");

    // final h in step-buffer 0 (SEQ even); f64 acc, same as R5-R9.
    if (j < 2 * CLASSES) {
        const int b = j >> 7;
        const int c = j & (CLASSES - 1);
        double acc = 0.0;
        for (int i = 0; i < HIDDEN; ++i) {
            acc += (double)hti[0][b][i] * (double)W_hy[i * CLASSES + c];
        }
        acc += (double)b_y[c];
        out[(size_t)(2 * g + b) * CLASSES + c] = (float)acc;
    }
}

extern "C" void kernel_launch(void* const* d_in, const int* in_sizes, int n_in,
                              void* d_out, int out_size, void* d_ws, size_t ws_size,
                              hipStream_t stream)
{
    const float *x, *W_hh, *W_xh, *W_hy, *b_h, *b_y;
    if (in_sizes[0] == BATCH * SEQ * IN_DIM) {
        x    = (const float*)d_in[0];
        W_hh = (const float*)d_in[1];
        W_xh = (const float*)d_in[2];
        W_hy = (const float*)d_in[3];
        b_h  = (const float*)d_in[4];
        b_y  = (const float*)d_in[5];
    } else {
        W_hh = (const float*)d_in[0];
        W_hy = (const float*)d_in[1];
        W_xh = (const float*)d_in[2];
        b_h  = (const float*)d_in[3];
        b_y  = (const float*)d_in[4];
        x    = (const float*)d_in[5];
    }
    float* out = (float*)d_out;
    (void)n_in; (void)out_size; (void)d_ws; (void)ws_size;

    rnn_fast<<<NWG, HIDDEN, 0, stream>>>(x, W_hh, W_xh, W_hy, b_h, b_y, out);
}